// Round 2
// baseline (442.934 us; speedup 1.0000x reference)
//
#include <hip/hip_runtime.h>

#define HID 512
#define GC  640
#define CC  320
#define GG  2
#define DHALF 128
#define MARGIN 0.05f

typedef __attribute__((ext_vector_type(8))) short short8v;
typedef __attribute__((ext_vector_type(4))) float float4v;

__device__ __forceinline__ unsigned short f2bf(float f) {
    unsigned u = __builtin_bit_cast(unsigned, f);
    u = (u + 0x7FFFu + ((u >> 16) & 1u)) >> 16;       // round-to-nearest-even
    return (unsigned short)u;
}

__device__ __forceinline__ void gload16(const void* g, void* l) {
    __builtin_amdgcn_global_load_lds(
        (const __attribute__((address_space(1))) void*)(unsigned long long)g,
        (__attribute__((address_space(3))) void*)(unsigned)(unsigned long long)l,
        16, 0, 0);
}

__global__ __launch_bounds__(256) void zero_misc(float* meanAcc, int* cnt) {
    for (int i = threadIdx.x; i < GC; i += 256) meanAcc[i] = 0.f;
    if (threadIdx.x == 0) *cnt = 0;
}

__global__ __launch_bounds__(256) void convert_bf16(
    const float* __restrict__ in, unsigned short* __restrict__ out, int n8)
{
    int i = blockIdx.x * 256 + threadIdx.x;
    if (i >= n8) return;
    const float4* p = (const float4*)in + (size_t)i * 2;
    float4 v0 = p[0], v1 = p[1];
    float f[8] = {v0.x, v0.y, v0.z, v0.w, v1.x, v1.y, v1.z, v1.w};
    unsigned r[4];
#pragma unroll
    for (int j = 0; j < 4; ++j)
        r[j] = (unsigned)f2bf(f[2*j]) | ((unsigned)f2bf(f[2*j+1]) << 16);
    uint4 o = {r[0], r[1], r[2], r[3]};
    *(uint4*)(out + (size_t)i * 8) = o;
}

// C[m][n] = sum_k Xb[m][k] * Wb[n][k]  (both row-major over k), + bq
__global__ __launch_bounds__(256) void gemm_bf16(
    const unsigned short* __restrict__ Xb,   // [CH][512] bf16
    const unsigned short* __restrict__ Wb,   // [640][512] bf16
    const float* __restrict__ bq,
    float* __restrict__ L)
{
    __shared__ __align__(16) unsigned short As[128 * 32];
    __shared__ __align__(16) unsigned short Bs[128 * 32];
    const int tid  = threadIdx.x;
    const int lane = tid & 63;
    const int wid  = tid >> 6;            // 0..3
    const int wr   = wid >> 1, wc = wid & 1;
    const int brow = blockIdx.x * 128;
    const int bcol = blockIdx.y * 128;

    float4v acc[4][4] = {};

    const int chunk = (wid * 2) * 64 + lane;          // first of 2 issues
    const int rowA0 = (chunk >> 2);
    const int k8A0  = (chunk & 3) * 8;
    const int chunk1 = (wid * 2 + 1) * 64 + lane;
    const int rowA1 = (chunk1 >> 2);
    const int k8A1  = (chunk1 & 3) * 8;

    for (int k0 = 0; k0 < HID; k0 += 32) {
        gload16(Xb + (size_t)(brow + rowA0) * HID + k0 + k8A0, &As[(wid * 2 + 0) * 512]);
        gload16(Xb + (size_t)(brow + rowA1) * HID + k0 + k8A1, &As[(wid * 2 + 1) * 512]);
        gload16(Wb + (size_t)(bcol + rowA0) * HID + k0 + k8A0, &Bs[(wid * 2 + 0) * 512]);
        gload16(Wb + (size_t)(bcol + rowA1) * HID + k0 + k8A1, &Bs[(wid * 2 + 1) * 512]);
        __syncthreads();
        short8v a[4], b[4];
#pragma unroll
        for (int t = 0; t < 4; ++t) {
            a[t] = *(const short8v*)&As[(wr * 64 + t * 16 + (lane & 15)) * 32 + (lane >> 4) * 8];
            b[t] = *(const short8v*)&Bs[(wc * 64 + t * 16 + (lane & 15)) * 32 + (lane >> 4) * 8];
        }
#pragma unroll
        for (int mt = 0; mt < 4; ++mt)
#pragma unroll
            for (int nt = 0; nt < 4; ++nt)
                acc[mt][nt] = __builtin_amdgcn_mfma_f32_16x16x32_bf16(a[mt], b[nt], acc[mt][nt], 0, 0, 0);
        __syncthreads();
    }
    // epilogue: C/D layout col=lane&15, row=(lane>>4)*4+r
#pragma unroll
    for (int mt = 0; mt < 4; ++mt) {
#pragma unroll
        for (int nt = 0; nt < 4; ++nt) {
            int col = bcol + wc * 64 + nt * 16 + (lane & 15);
            float bias = bq[col];
#pragma unroll
            for (int r = 0; r < 4; ++r) {
                int row = brow + wr * 64 + mt * 16 + (lane >> 4) * 4 + r;
                L[(size_t)row * GC + col] = acc[mt][nt][r] + bias;
            }
        }
    }
}

__global__ __launch_bounds__(256) void postproc(
    const float* __restrict__ L, const float* __restrict__ gum,
    const float* __restrict__ cv, float* __restrict__ out,
    float* __restrict__ meanAcc, int* __restrict__ cnt,
    int* __restrict__ flags, int tok0)
{
    __shared__ float smean[GC];
    for (int i = threadIdx.x; i < GC; i += 256) smean[i] = 0.f;
    __syncthreads();

    const int lane  = threadIdx.x & 63;
    const int wid   = threadIdx.x >> 6;
    const int g     = wid >> 1;
    const int tloc0 = blockIdx.x * 64 + (wid & 1) * 32;

    float macc[5] = {0.f, 0.f, 0.f, 0.f, 0.f};

    for (int t = 0; t < 32; ++t) {
        const int tloc  = tloc0 + t;
        const int tglob = tok0 + tloc;
        const float* lrow = L   + (size_t)tloc * GC + g * CC;
        const float* grow = gum + ((size_t)tglob * GG + g) * CC;
        float l[5], gm[5];
#pragma unroll
        for (int j = 0; j < 5; ++j) {
            int c = lane + j * 64;
            l[j]  = lrow[c];
            gm[j] = grow[c];
        }
        // plain softmax(logits) accumulate for mean_p
        float mx = fmaxf(fmaxf(fmaxf(l[0], l[1]), fmaxf(l[2], l[3])), l[4]);
#pragma unroll
        for (int m = 32; m; m >>= 1) mx = fmaxf(mx, __shfl_xor(mx, m, 64));
        float e[5], s = 0.f;
#pragma unroll
        for (int j = 0; j < 5; ++j) { e[j] = __expf(l[j] - mx); s += e[j]; }
#pragma unroll
        for (int m = 32; m; m >>= 1) s += __shfl_xor(s, m, 64);
        float inv = 1.f / s;
#pragma unroll
        for (int j = 0; j < 5; ++j) macc[j] += e[j] * inv;

        // top-2 of (logits + gumbel): argmax + ambiguity gap
        float b  = l[0] + gm[0];
        int   bi = lane;
        float s2 = -3.0e38f;
#pragma unroll
        for (int j = 1; j < 5; ++j) {
            float v = l[j] + gm[j]; int c = lane + j * 64;
            if (v > b) { s2 = b; b = v; bi = c; }
            else if (v > s2) s2 = v;
        }
#pragma unroll
        for (int m = 32; m; m >>= 1) {
            float ob = __shfl_xor(b, m, 64);
            int  obi = __shfl_xor(bi, m, 64);
            float os = __shfl_xor(s2, m, 64);
            if (ob > b || (ob == b && obi < bi)) { s2 = fmaxf(os, b); b = ob; bi = obi; }
            else                                 { s2 = fmaxf(s2, ob); }
        }
        if (lane == 0 && (b - s2) < MARGIN) {
            int p = atomicAdd(cnt, 1);
            flags[p] = tglob * GG + g;
        }
        // gather selected codevector (coalesced float2 per lane)
        const float* cvp = cv + (size_t)(g * CC + bi) * DHALF;
        float2 cvv = *(const float2*)(cvp + lane * 2);
        *(float2*)(out + (size_t)tglob * 256 + g * DHALF + lane * 2) = cvv;
    }
#pragma unroll
    for (int j = 0; j < 5; ++j)
        atomicAdd(&smean[g * CC + lane + j * 64], macc[j]);
    __syncthreads();
    for (int i = threadIdx.x; i < GC; i += 256)
        atomicAdd(&meanAcc[i], smean[i]);
}

// exact fp32 recompute of argmax for flagged (near-tie) rows
__global__ __launch_bounds__(256) void fixup(
    const float* __restrict__ X, const float* __restrict__ W,
    const float* __restrict__ bq, const float* __restrict__ gum,
    const float* __restrict__ cv, float* __restrict__ out,
    const int* __restrict__ flags, const int* __restrict__ cnt)
{
    __shared__ float xs[HID];
    __shared__ float vals[CC];
    __shared__ int sidx;
    const int n = *cnt;
    const int tid = threadIdx.x;
    for (int i = blockIdx.x; i < n; i += gridDim.x) {
        const int row = flags[i];
        const int tok = row >> 1, g = row & 1;
        for (int k = tid; k < HID; k += 256) xs[k] = X[(size_t)tok * HID + k];
        __syncthreads();
        for (int c = tid; c < CC; c += 256) {
            const float* wr = W + (size_t)(g * CC + c) * HID;
            float s = 0.f;
            for (int k = 0; k < HID; ++k) s = fmaf(xs[k], wr[k], s);
            vals[c] = s + bq[g * CC + c] + gum[(size_t)row * CC + c];
        }
        __syncthreads();
        if (tid < 64) {
            float b = -3.0e38f; int bi = 0;
#pragma unroll
            for (int j = 0; j < 5; ++j) {
                int c = tid * 5 + j;
                float v = vals[c];
                if (v > b) { b = v; bi = c; }
            }
#pragma unroll
            for (int m = 32; m; m >>= 1) {
                float ob = __shfl_xor(b, m, 64);
                int  obi = __shfl_xor(bi, m, 64);
                if (ob > b || (ob == b && obi < bi)) { b = ob; bi = obi; }
            }
            if (tid == 0) sidx = bi;
        }
        __syncthreads();
        const int bi = sidx;
        if (tid < 128)
            out[(size_t)tok * 256 + g * DHALF + tid] = cv[((size_t)(g * CC + bi)) * DHALF + tid];
        __syncthreads();
    }
}

__global__ __launch_bounds__(256) void perpk(
    const float* __restrict__ meanAcc, float* __restrict__ outp, int ntot)
{
    __shared__ float red0[256];
    __shared__ float red1[256];
    const float invn = 1.f / (float)ntot;
    float h0 = 0.f, h1 = 0.f;
    for (int c = threadIdx.x; c < CC; c += 256) {
        float p0 = meanAcc[c]      * invn;
        float p1 = meanAcc[CC + c] * invn;
        h0 -= p0 * logf(p0 + 1e-7f);
        h1 -= p1 * logf(p1 + 1e-7f);
    }
    red0[threadIdx.x] = h0; red1[threadIdx.x] = h1;
    __syncthreads();
    for (int s = 128; s; s >>= 1) {
        if (threadIdx.x < (unsigned)s) {
            red0[threadIdx.x] += red0[threadIdx.x + s];
            red1[threadIdx.x] += red1[threadIdx.x + s];
        }
        __syncthreads();
    }
    if (threadIdx.x == 0) outp[0] = expf(red0[0]) + expf(red1[0]);
}

extern "C" void kernel_launch(void* const* d_in, const int* in_sizes, int n_in,
                              void* d_out, int out_size, void* d_ws, size_t ws_size,
                              hipStream_t stream) {
    const float* x      = (const float*)d_in[0];
    const float* gumbel = (const float*)d_in[1];
    const float* Wq     = (const float*)d_in[2];
    const float* bq     = (const float*)d_in[3];
    const float* cv     = (const float*)d_in[4];
    float* out = (float*)d_out;

    const int NT = in_sizes[0] / HID;       // 32768 tokens

    char* wsc = (char*)d_ws;
    float* meanAcc = (float*)wsc;                        // 640 f
    int*   cnt     = (int*)(wsc + 2560);
    int*   flags   = (int*)(wsc + 4096);                 // up to 65536 ints
    unsigned short* Wb = (unsigned short*)(wsc + 266240);// 640*512 bf16 = 655360 B
    const size_t base = 921600;

    // chunk sizing: per token Xb (1024 B) + logits (2560 B)
    size_t avail = ws_size > base ? ws_size - base : 0;
    long maxTok = (long)(avail / 3584);
    int CH = (int)((maxTok / 128) * 128);
    if (CH > NT) CH = NT;
    if (CH < 128) CH = 128;
    unsigned short* Xb = (unsigned short*)(wsc + base);
    float* Lbuf = (float*)(wsc + base + (size_t)CH * 1024);

    zero_misc<<<1, 256, 0, stream>>>(meanAcc, cnt);
    convert_bf16<<<(GC * HID / 8 + 255) / 256, 256, 0, stream>>>(Wq, Wb, GC * HID / 8);

    for (int t0 = 0; t0 < NT; t0 += CH) {
        int cur = NT - t0 < CH ? NT - t0 : CH;
        int n8 = cur * HID / 8;
        convert_bf16<<<(n8 + 255) / 256, 256, 0, stream>>>(
            x + (size_t)t0 * HID, Xb, n8);
        dim3 ggrid(cur / 128, GC / 128);
        gemm_bf16<<<ggrid, 256, 0, stream>>>(Xb, Wb, bq, Lbuf);
        postproc<<<cur / 64, 256, 0, stream>>>(Lbuf, gumbel, cv, out, meanAcc, cnt, flags, t0);
    }
    fixup<<<256, 256, 0, stream>>>(x, Wq, bq, gumbel, cv, out, flags, cnt);
    perpk<<<1, 256, 0, stream>>>(meanAcc, out + (size_t)out_size - 1, NT);
}

// Round 3
// 201.925 us; speedup vs baseline: 2.1936x; 2.1936x over previous
//
#include <hip/hip_runtime.h>

#define HID 512
#define GC  640
#define CC  320
#define GG  2
#define DHALF 128
#define MARGIN 0.02f
#define FB 16

typedef __attribute__((ext_vector_type(8))) short short8v;
typedef __attribute__((ext_vector_type(4))) float float4v;

__device__ __forceinline__ unsigned short f2bf(float f) {
    unsigned u = __builtin_bit_cast(unsigned, f);
    u = (u + 0x7FFFu + ((u >> 16) & 1u)) >> 16;       // round-to-nearest-even
    return (unsigned short)u;
}

__device__ __forceinline__ void gload16(const void* g, void* l) {
    __builtin_amdgcn_global_load_lds(
        (const __attribute__((address_space(1))) void*)(unsigned long long)g,
        (__attribute__((address_space(3))) void*)(unsigned)(unsigned long long)l,
        16, 0, 0);
}

__global__ __launch_bounds__(256) void zero_misc(float* meanAcc, int* cnt) {
    for (int i = threadIdx.x; i < GC; i += 256) meanAcc[i] = 0.f;
    if (threadIdx.x < 2) cnt[threadIdx.x] = 0;
}

__global__ __launch_bounds__(256) void convert_bf16(
    const float* __restrict__ in, unsigned short* __restrict__ out, int n8)
{
    int i = blockIdx.x * 256 + threadIdx.x;
    if (i >= n8) return;
    const float4* p = (const float4*)in + (size_t)i * 2;
    float4 v0 = p[0], v1 = p[1];
    float f[8] = {v0.x, v0.y, v0.z, v0.w, v1.x, v1.y, v1.z, v1.w};
    unsigned r[4];
#pragma unroll
    for (int j = 0; j < 4; ++j)
        r[j] = (unsigned)f2bf(f[2*j]) | ((unsigned)f2bf(f[2*j+1]) << 16);
    uint4 o = {r[0], r[1], r[2], r[3]};
    *(uint4*)(out + (size_t)i * 8) = o;
}

// C[m][n] = sum_k Xb[m][k] * Wb[n][k] (+ bq)
__global__ __launch_bounds__(256) void gemm_bf16(
    const unsigned short* __restrict__ Xb,
    const unsigned short* __restrict__ Wb,
    const float* __restrict__ bq,
    float* __restrict__ L)
{
    __shared__ __align__(16) unsigned short As[128 * 32];
    __shared__ __align__(16) unsigned short Bs[128 * 32];
    const int tid  = threadIdx.x;
    const int lane = tid & 63;
    const int wid  = tid >> 6;
    const int wr   = wid >> 1, wc = wid & 1;
    const int brow = blockIdx.x * 128;
    const int bcol = blockIdx.y * 128;

    float4v acc[4][4] = {};

    const int chunk = (wid * 2) * 64 + lane;
    const int rowA0 = (chunk >> 2);
    const int k8A0  = (chunk & 3) * 8;
    const int chunk1 = (wid * 2 + 1) * 64 + lane;
    const int rowA1 = (chunk1 >> 2);
    const int k8A1  = (chunk1 & 3) * 8;

    for (int k0 = 0; k0 < HID; k0 += 32) {
        gload16(Xb + (size_t)(brow + rowA0) * HID + k0 + k8A0, &As[(wid * 2 + 0) * 512]);
        gload16(Xb + (size_t)(brow + rowA1) * HID + k0 + k8A1, &As[(wid * 2 + 1) * 512]);
        gload16(Wb + (size_t)(bcol + rowA0) * HID + k0 + k8A0, &Bs[(wid * 2 + 0) * 512]);
        gload16(Wb + (size_t)(bcol + rowA1) * HID + k0 + k8A1, &Bs[(wid * 2 + 1) * 512]);
        __syncthreads();
        short8v a[4], b[4];
#pragma unroll
        for (int t = 0; t < 4; ++t) {
            a[t] = *(const short8v*)&As[(wr * 64 + t * 16 + (lane & 15)) * 32 + (lane >> 4) * 8];
            b[t] = *(const short8v*)&Bs[(wc * 64 + t * 16 + (lane & 15)) * 32 + (lane >> 4) * 8];
        }
#pragma unroll
        for (int mt = 0; mt < 4; ++mt)
#pragma unroll
            for (int nt = 0; nt < 4; ++nt)
                acc[mt][nt] = __builtin_amdgcn_mfma_f32_16x16x32_bf16(a[mt], b[nt], acc[mt][nt], 0, 0, 0);
        __syncthreads();
    }
#pragma unroll
    for (int mt = 0; mt < 4; ++mt) {
#pragma unroll
        for (int nt = 0; nt < 4; ++nt) {
            int col = bcol + wc * 64 + nt * 16 + (lane & 15);
            float bias = bq[col];
#pragma unroll
            for (int r = 0; r < 4; ++r) {
                int row = brow + wr * 64 + mt * 16 + (lane >> 4) * 4 + r;
                L[(size_t)row * GC + col] = acc[mt][nt][r] + bias;
            }
        }
    }
}

__global__ __launch_bounds__(256) void postproc(
    const float* __restrict__ L, const float* __restrict__ gum,
    const float* __restrict__ cv, float* __restrict__ out,
    float* __restrict__ meanAcc, int* __restrict__ cnt,
    int* __restrict__ flags0, int* __restrict__ flags1, int tok0)
{
    __shared__ float smean[GC];
    for (int i = threadIdx.x; i < GC; i += 256) smean[i] = 0.f;
    __syncthreads();

    const int lane  = threadIdx.x & 63;
    const int wid   = threadIdx.x >> 6;
    const int g     = wid >> 1;
    const int tloc0 = blockIdx.x * 64 + (wid & 1) * 32;
    int* flagsg = g ? flags1 : flags0;

    float macc[5] = {0.f, 0.f, 0.f, 0.f, 0.f};

    for (int t = 0; t < 32; ++t) {
        const int tloc  = tloc0 + t;
        const int tglob = tok0 + tloc;
        const float* lrow = L   + (size_t)tloc * GC + g * CC;
        const float* grow = gum + ((size_t)tglob * GG + g) * CC;
        float l[5], gm[5];
#pragma unroll
        for (int j = 0; j < 5; ++j) {
            int c = lane + j * 64;
            l[j]  = lrow[c];
            gm[j] = grow[c];
        }
        float mx = fmaxf(fmaxf(fmaxf(l[0], l[1]), fmaxf(l[2], l[3])), l[4]);
#pragma unroll
        for (int m = 32; m; m >>= 1) mx = fmaxf(mx, __shfl_xor(mx, m, 64));
        float e[5], s = 0.f;
#pragma unroll
        for (int j = 0; j < 5; ++j) { e[j] = __expf(l[j] - mx); s += e[j]; }
#pragma unroll
        for (int m = 32; m; m >>= 1) s += __shfl_xor(s, m, 64);
        float inv = 1.f / s;
#pragma unroll
        for (int j = 0; j < 5; ++j) macc[j] += e[j] * inv;

        // top-2 of (logits + gumbel)
        float b  = l[0] + gm[0];
        int   bi = lane;
        float s2 = -3.0e38f;
#pragma unroll
        for (int j = 1; j < 5; ++j) {
            float v = l[j] + gm[j]; int c = lane + j * 64;
            if (v > b) { s2 = b; b = v; bi = c; }
            else if (v > s2) s2 = v;
        }
#pragma unroll
        for (int m = 32; m; m >>= 1) {
            float ob = __shfl_xor(b, m, 64);
            int  obi = __shfl_xor(bi, m, 64);
            float os = __shfl_xor(s2, m, 64);
            if (ob > b || (ob == b && obi < bi)) { s2 = fmaxf(os, b); b = ob; bi = obi; }
            else                                 { s2 = fmaxf(s2, ob); }
        }
        if (lane == 0 && (b - s2) < MARGIN) {
            int p = atomicAdd(&cnt[g], 1);
            flagsg[p] = tglob;
        }
        const float* cvp = cv + (size_t)(g * CC + bi) * DHALF;
        float2 cvv = *(const float2*)(cvp + lane * 2);
        *(float2*)(out + (size_t)tglob * 256 + g * DHALF + lane * 2) = cvv;
    }
#pragma unroll
    for (int j = 0; j < 5; ++j)
        atomicAdd(&smean[g * CC + lane + j * 64], macc[j]);
    __syncthreads();
    for (int i = threadIdx.x; i < GC; i += 256)
        atomicAdd(&meanAcc[i], smean[i]);
}

// Batched exact fp32 recompute for flagged rows: 16 rows share one W pass.
// 320 threads = 5 waves: one code per thread.
__global__ __launch_bounds__(320) void fixup(
    const float* __restrict__ X, const float* __restrict__ W,
    const float* __restrict__ bq, const float* __restrict__ gum,
    const float* __restrict__ cv, float* __restrict__ out,
    const int* __restrict__ flags0, const int* __restrict__ flags1,
    const int* __restrict__ cnt)
{
    __shared__ float xs[FB][HID];     // 32 KB
    __shared__ float vals[FB][CC];    // 20 KB
    __shared__ int stok[FB];
    const int tid = threadIdx.x;
    const int n0 = cnt[0], n1 = cnt[1];
    const int nb0 = (n0 + FB - 1) / FB;
    const int nb1 = (n1 + FB - 1) / FB;

    for (int bb = blockIdx.x; bb < nb0 + nb1; bb += gridDim.x) {
        const int g    = (bb < nb0) ? 0 : 1;
        const int lb   = (bb < nb0) ? bb : bb - nb0;
        const int n    = g ? n1 : n0;
        const int* fl  = g ? flags1 : flags0;
        const int r0   = lb * FB;
        const int nr   = (n - r0 < FB) ? (n - r0) : FB;

        if (tid < FB) {
            int idx = r0 + tid;
            if (idx >= n) idx = n - 1;
            stok[tid] = fl[idx];
        }
        __syncthreads();
        // stage X rows (pad rows repeat last valid -> harmless compute)
        for (int i = tid; i < FB * (HID / 4); i += 320) {
            int r = i >> 7, k4 = i & 127;
            *(float4*)&xs[r][k4 * 4] = *(const float4*)(X + (size_t)stok[r] * HID + k4 * 4);
        }
        __syncthreads();

        {
            const int c = tid;          // exactly one code per thread
            if (c < CC) {
                const float* wr = W + (size_t)(g * CC + c) * HID;
                float acc[FB];
#pragma unroll
                for (int r = 0; r < FB; ++r) acc[r] = 0.f;
                for (int k4 = 0; k4 < HID / 4; ++k4) {
                    float4 w4 = *(const float4*)(wr + k4 * 4);
#pragma unroll
                    for (int r = 0; r < FB; ++r) {
                        float4 xv = *(const float4*)&xs[r][k4 * 4];
                        acc[r] = fmaf(xv.x, w4.x, acc[r]);
                        acc[r] = fmaf(xv.y, w4.y, acc[r]);
                        acc[r] = fmaf(xv.z, w4.z, acc[r]);
                        acc[r] = fmaf(xv.w, w4.w, acc[r]);
                    }
                }
                float bias = bq[g * CC + c];
#pragma unroll
                for (int r = 0; r < FB; ++r)
                    vals[r][c] = acc[r] + bias + gum[((size_t)stok[r] * GG + g) * CC + c];
            }
        }
        __syncthreads();

        // argmax + gather: waves 0..3 handle 4 rows each
        const int lane = tid & 63;
        const int wid  = tid >> 6;
        if (wid < 4) {
#pragma unroll
            for (int rr = 0; rr < 4; ++rr) {
                int r = wid * 4 + rr;
                if (r < nr) {
                    float b = -3.0e38f; int bi = 0;
#pragma unroll
                    for (int j = 0; j < 5; ++j) {
                        int c = lane + j * 64;
                        float v = vals[r][c];
                        if (v > b || (v == b && c < bi)) { b = v; bi = c; }
                    }
#pragma unroll
                    for (int m = 32; m; m >>= 1) {
                        float ob = __shfl_xor(b, m, 64);
                        int  obi = __shfl_xor(bi, m, 64);
                        if (ob > b || (ob == b && obi < bi)) { b = ob; bi = obi; }
                    }
                    int tok = stok[r];
                    float2 cvv = *(const float2*)(cv + ((size_t)(g * CC + bi)) * DHALF + lane * 2);
                    *(float2*)(out + (size_t)tok * 256 + g * DHALF + lane * 2) = cvv;
                }
            }
        }
        __syncthreads();
    }
}

__global__ __launch_bounds__(256) void perpk(
    const float* __restrict__ meanAcc, float* __restrict__ outp, int ntot)
{
    __shared__ float red0[256];
    __shared__ float red1[256];
    const float invn = 1.f / (float)ntot;
    float h0 = 0.f, h1 = 0.f;
    for (int c = threadIdx.x; c < CC; c += 256) {
        float p0 = meanAcc[c]      * invn;
        float p1 = meanAcc[CC + c] * invn;
        h0 -= p0 * logf(p0 + 1e-7f);
        h1 -= p1 * logf(p1 + 1e-7f);
    }
    red0[threadIdx.x] = h0; red1[threadIdx.x] = h1;
    __syncthreads();
    for (int s = 128; s; s >>= 1) {
        if (threadIdx.x < (unsigned)s) {
            red0[threadIdx.x] += red0[threadIdx.x + s];
            red1[threadIdx.x] += red1[threadIdx.x + s];
        }
        __syncthreads();
    }
    if (threadIdx.x == 0) outp[0] = expf(red0[0]) + expf(red1[0]);
}

extern "C" void kernel_launch(void* const* d_in, const int* in_sizes, int n_in,
                              void* d_out, int out_size, void* d_ws, size_t ws_size,
                              hipStream_t stream) {
    const float* x      = (const float*)d_in[0];
    const float* gumbel = (const float*)d_in[1];
    const float* Wq     = (const float*)d_in[2];
    const float* bq     = (const float*)d_in[3];
    const float* cv     = (const float*)d_in[4];
    float* out = (float*)d_out;

    const int NT = in_sizes[0] / HID;       // 32768 tokens

    char* wsc = (char*)d_ws;
    float* meanAcc = (float*)wsc;                          // 640 f
    int*   cnt     = (int*)(wsc + 2560);                   // 2 ints
    int*   flags0  = (int*)(wsc + 4096);                   // 32768 ints
    int*   flags1  = (int*)(wsc + 135168);                 // 32768 ints
    unsigned short* Wb = (unsigned short*)(wsc + 266240);  // 640*512 bf16
    const size_t base = 921600;

    size_t avail = ws_size > base ? ws_size - base : 0;
    long maxTok = (long)(avail / 3584);
    int CH = (int)((maxTok / 128) * 128);
    if (CH > NT) CH = NT;
    if (CH < 128) CH = 128;
    unsigned short* Xb = (unsigned short*)(wsc + base);
    float* Lbuf = (float*)(wsc + base + (size_t)CH * 1024);

    zero_misc<<<1, 256, 0, stream>>>(meanAcc, cnt);
    convert_bf16<<<(GC * HID / 8 + 255) / 256, 256, 0, stream>>>(Wq, Wb, GC * HID / 8);

    for (int t0 = 0; t0 < NT; t0 += CH) {
        int cur = NT - t0 < CH ? NT - t0 : CH;
        int n8 = cur * HID / 8;
        convert_bf16<<<(n8 + 255) / 256, 256, 0, stream>>>(
            x + (size_t)t0 * HID, Xb, n8);
        dim3 ggrid(cur / 128, GC / 128);
        gemm_bf16<<<ggrid, 256, 0, stream>>>(Xb, Wb, bq, Lbuf);
        postproc<<<cur / 64, 256, 0, stream>>>(Lbuf, gumbel, cv, out, meanAcc, cnt,
                                               flags0, flags1, t0);
    }
    fixup<<<256, 320, 0, stream>>>(x, Wq, bq, gumbel, cv, out, flags0, flags1, cnt);
    perpk<<<1, 256, 0, stream>>>(meanAcc, out + (size_t)out_size - 1, NT);
}

// Round 4
// 175.030 us; speedup vs baseline: 2.5306x; 1.1537x over previous
//
#include <hip/hip_runtime.h>

#define HID 512
#define GC  640
#define CC  320
#define GG  2
#define DHALF 128
#define MARGIN 0.02f
#define FB 16

typedef __attribute__((ext_vector_type(8))) short short8v;
typedef __attribute__((ext_vector_type(4))) float float4v;

__device__ __forceinline__ unsigned short f2bf(float f) {
    unsigned u = __builtin_bit_cast(unsigned, f);
    u = (u + 0x7FFFu + ((u >> 16) & 1u)) >> 16;       // round-to-nearest-even
    return (unsigned short)u;
}

__device__ __forceinline__ void gload16(const void* g, void* l) {
    __builtin_amdgcn_global_load_lds(
        (const __attribute__((address_space(1))) void*)(unsigned long long)g,
        (__attribute__((address_space(3))) void*)(unsigned)(unsigned long long)l,
        16, 0, 0);
}

__global__ __launch_bounds__(256) void zero_misc(float* meanAcc, int* cnt) {
    for (int i = threadIdx.x; i < GC; i += 256) meanAcc[i] = 0.f;
    if (threadIdx.x < 2) cnt[threadIdx.x] = 0;
}

__global__ __launch_bounds__(256) void convert_bf16(
    const float* __restrict__ in, unsigned short* __restrict__ out, int n8)
{
    int i = blockIdx.x * 256 + threadIdx.x;
    if (i >= n8) return;
    const float4* p = (const float4*)in + (size_t)i * 2;
    float4 v0 = p[0], v1 = p[1];
    float f[8] = {v0.x, v0.y, v0.z, v0.w, v1.x, v1.y, v1.z, v1.w};
    unsigned r[4];
#pragma unroll
    for (int j = 0; j < 4; ++j)
        r[j] = (unsigned)f2bf(f[2*j]) | ((unsigned)f2bf(f[2*j+1]) << 16);
    uint4 o = {r[0], r[1], r[2], r[3]};
    *(uint4*)(out + (size_t)i * 8) = o;
}

// C[m][n] = sum_k Xb[m][k] * Wb[n][k] (+ bq)
__global__ __launch_bounds__(256) void gemm_bf16(
    const unsigned short* __restrict__ Xb,
    const unsigned short* __restrict__ Wb,
    const float* __restrict__ bq,
    float* __restrict__ L)
{
    __shared__ __align__(16) unsigned short As[128 * 32];
    __shared__ __align__(16) unsigned short Bs[128 * 32];
    const int tid  = threadIdx.x;
    const int lane = tid & 63;
    const int wid  = tid >> 6;
    const int wr   = wid >> 1, wc = wid & 1;
    const int brow = blockIdx.x * 128;
    const int bcol = blockIdx.y * 128;

    float4v acc[4][4] = {};

    const int chunk = (wid * 2) * 64 + lane;
    const int rowA0 = (chunk >> 2);
    const int k8A0  = (chunk & 3) * 8;
    const int chunk1 = (wid * 2 + 1) * 64 + lane;
    const int rowA1 = (chunk1 >> 2);
    const int k8A1  = (chunk1 & 3) * 8;

    for (int k0 = 0; k0 < HID; k0 += 32) {
        gload16(Xb + (size_t)(brow + rowA0) * HID + k0 + k8A0, &As[(wid * 2 + 0) * 512]);
        gload16(Xb + (size_t)(brow + rowA1) * HID + k0 + k8A1, &As[(wid * 2 + 1) * 512]);
        gload16(Wb + (size_t)(bcol + rowA0) * HID + k0 + k8A0, &Bs[(wid * 2 + 0) * 512]);
        gload16(Wb + (size_t)(bcol + rowA1) * HID + k0 + k8A1, &Bs[(wid * 2 + 1) * 512]);
        __syncthreads();
        short8v a[4], b[4];
#pragma unroll
        for (int t = 0; t < 4; ++t) {
            a[t] = *(const short8v*)&As[(wr * 64 + t * 16 + (lane & 15)) * 32 + (lane >> 4) * 8];
            b[t] = *(const short8v*)&Bs[(wc * 64 + t * 16 + (lane & 15)) * 32 + (lane >> 4) * 8];
        }
#pragma unroll
        for (int mt = 0; mt < 4; ++mt)
#pragma unroll
            for (int nt = 0; nt < 4; ++nt)
                acc[mt][nt] = __builtin_amdgcn_mfma_f32_16x16x32_bf16(a[mt], b[nt], acc[mt][nt], 0, 0, 0);
        __syncthreads();
    }
#pragma unroll
    for (int mt = 0; mt < 4; ++mt) {
#pragma unroll
        for (int nt = 0; nt < 4; ++nt) {
            int col = bcol + wc * 64 + nt * 16 + (lane & 15);
            float bias = bq[col];
#pragma unroll
            for (int r = 0; r < 4; ++r) {
                int row = brow + wr * 64 + mt * 16 + (lane >> 4) * 4 + r;
                L[(size_t)row * GC + col] = acc[mt][nt][r] + bias;
            }
        }
    }
}

// 512 threads = 8 waves; waves 0-3 -> group 0, 4-7 -> group 1; 8 tokens per wave.
__global__ __launch_bounds__(512) void postproc(
    const float* __restrict__ L, const float* __restrict__ gum,
    const float* __restrict__ cv, float* __restrict__ out,
    float* __restrict__ meanAcc, int* __restrict__ cnt,
    int* __restrict__ flags0, int* __restrict__ flags1, int tok0)
{
    __shared__ float smean[GC];
    for (int i = threadIdx.x; i < GC; i += 512) smean[i] = 0.f;
    __syncthreads();

    const int lane  = threadIdx.x & 63;
    const int wid   = threadIdx.x >> 6;          // 0..7
    const int g     = wid >> 2;
    const int tloc0 = blockIdx.x * 32 + (wid & 3) * 8;
    int* flagsg = g ? flags1 : flags0;

    float macc[5] = {0.f, 0.f, 0.f, 0.f, 0.f};

    for (int t = 0; t < 8; ++t) {
        const int tloc  = tloc0 + t;
        const int tglob = tok0 + tloc;
        const float* lrow = L   + (size_t)tloc * GC + g * CC;
        const float* grow = gum + ((size_t)tglob * GG + g) * CC;
        float l[5], gm[5];
#pragma unroll
        for (int j = 0; j < 5; ++j) {
            int c = lane + j * 64;
            l[j]  = lrow[c];
            gm[j] = grow[c];
        }
        // softmax without max-sub (logits ~ N(0,1); |max| < ~6 over 4e7 draws)
        float e[5];
        float s = 0.f;
#pragma unroll
        for (int j = 0; j < 5; ++j) { e[j] = __expf(l[j]); s += e[j]; }

        // per-lane top-2 of (logits + gumbel)
        float b  = l[0] + gm[0];
        int   bi = lane;
        float s2 = -3.0e38f;
#pragma unroll
        for (int j = 1; j < 5; ++j) {
            float v = l[j] + gm[j]; int c = lane + j * 64;
            if (v > b) { s2 = b; b = v; bi = c; }
            else if (v > s2) s2 = v;
        }
        // single fused 6-step reduce: sum + (max, idx, second)
#pragma unroll
        for (int m = 32; m; m >>= 1) {
            float os  = __shfl_xor(s,  m, 64);
            float ob  = __shfl_xor(b,  m, 64);
            int   obi = __shfl_xor(bi, m, 64);
            float os2 = __shfl_xor(s2, m, 64);
            s += os;
            if (ob > b || (ob == b && obi < bi)) { s2 = fmaxf(os2, b); b = ob; bi = obi; }
            else                                 { s2 = fmaxf(s2, ob); }
        }
        float inv = 1.f / s;
#pragma unroll
        for (int j = 0; j < 5; ++j) macc[j] += e[j] * inv;

        if (lane == 0 && (b - s2) < MARGIN) {
            int p = atomicAdd(&cnt[g], 1);
            flagsg[p] = tglob;
        }
        const float* cvp = cv + (size_t)(g * CC + bi) * DHALF;
        float2 cvv = *(const float2*)(cvp + lane * 2);
        *(float2*)(out + (size_t)tglob * 256 + g * DHALF + lane * 2) = cvv;
    }
#pragma unroll
    for (int j = 0; j < 5; ++j)
        atomicAdd(&smean[g * CC + lane + j * 64], macc[j]);
    __syncthreads();
    for (int i = threadIdx.x; i < GC; i += 512)
        atomicAdd(&meanAcc[i], smean[i]);
}

// Batched exact fp32 recompute for flagged rows: 16 rows share one W pass.
__global__ __launch_bounds__(320) void fixup(
    const float* __restrict__ X, const float* __restrict__ W,
    const float* __restrict__ bq, const float* __restrict__ gum,
    const float* __restrict__ cv, float* __restrict__ out,
    const int* __restrict__ flags0, const int* __restrict__ flags1,
    const int* __restrict__ cnt)
{
    __shared__ float xs[FB][HID];
    __shared__ float vals[FB][CC];
    __shared__ int stok[FB];
    const int tid = threadIdx.x;
    const int n0 = cnt[0], n1 = cnt[1];
    const int nb0 = (n0 + FB - 1) / FB;
    const int nb1 = (n1 + FB - 1) / FB;

    for (int bb = blockIdx.x; bb < nb0 + nb1; bb += gridDim.x) {
        const int g    = (bb < nb0) ? 0 : 1;
        const int lb   = (bb < nb0) ? bb : bb - nb0;
        const int n    = g ? n1 : n0;
        const int* fl  = g ? flags1 : flags0;
        const int r0   = lb * FB;
        const int nr   = (n - r0 < FB) ? (n - r0) : FB;

        if (tid < FB) {
            int idx = r0 + tid;
            if (idx >= n) idx = n - 1;
            stok[tid] = fl[idx];
        }
        __syncthreads();
        for (int i = tid; i < FB * (HID / 4); i += 320) {
            int r = i >> 7, k4 = i & 127;
            *(float4*)&xs[r][k4 * 4] = *(const float4*)(X + (size_t)stok[r] * HID + k4 * 4);
        }
        __syncthreads();

        {
            const int c = tid;
            if (c < CC) {
                const float* wr = W + (size_t)(g * CC + c) * HID;
                float acc[FB];
#pragma unroll
                for (int r = 0; r < FB; ++r) acc[r] = 0.f;
                for (int k4 = 0; k4 < HID / 4; ++k4) {
                    float4 w4 = *(const float4*)(wr + k4 * 4);
#pragma unroll
                    for (int r = 0; r < FB; ++r) {
                        float4 xv = *(const float4*)&xs[r][k4 * 4];
                        acc[r] = fmaf(xv.x, w4.x, acc[r]);
                        acc[r] = fmaf(xv.y, w4.y, acc[r]);
                        acc[r] = fmaf(xv.z, w4.z, acc[r]);
                        acc[r] = fmaf(xv.w, w4.w, acc[r]);
                    }
                }
                float bias = bq[g * CC + c];
#pragma unroll
                for (int r = 0; r < FB; ++r)
                    vals[r][c] = acc[r] + bias + gum[((size_t)stok[r] * GG + g) * CC + c];
            }
        }
        __syncthreads();

        const int lane = tid & 63;
        const int wid  = tid >> 6;
        if (wid < 4) {
#pragma unroll
            for (int rr = 0; rr < 4; ++rr) {
                int r = wid * 4 + rr;
                if (r < nr) {
                    float b = -3.0e38f; int bi = 0;
#pragma unroll
                    for (int j = 0; j < 5; ++j) {
                        int c = lane + j * 64;
                        float v = vals[r][c];
                        if (v > b || (v == b && c < bi)) { b = v; bi = c; }
                    }
#pragma unroll
                    for (int m = 32; m; m >>= 1) {
                        float ob = __shfl_xor(b, m, 64);
                        int  obi = __shfl_xor(bi, m, 64);
                        if (ob > b || (ob == b && obi < bi)) { b = ob; bi = obi; }
                    }
                    int tok = stok[r];
                    float2 cvv = *(const float2*)(cv + ((size_t)(g * CC + bi)) * DHALF + lane * 2);
                    *(float2*)(out + (size_t)tok * 256 + g * DHALF + lane * 2) = cvv;
                }
            }
        }
        __syncthreads();
    }
}

__global__ __launch_bounds__(256) void perpk(
    const float* __restrict__ meanAcc, float* __restrict__ outp, int ntot)
{
    __shared__ float red0[256];
    __shared__ float red1[256];
    const float invn = 1.f / (float)ntot;
    float h0 = 0.f, h1 = 0.f;
    for (int c = threadIdx.x; c < CC; c += 256) {
        float p0 = meanAcc[c]      * invn;
        float p1 = meanAcc[CC + c] * invn;
        h0 -= p0 * logf(p0 + 1e-7f);
        h1 -= p1 * logf(p1 + 1e-7f);
    }
    red0[threadIdx.x] = h0; red1[threadIdx.x] = h1;
    __syncthreads();
    for (int s = 128; s; s >>= 1) {
        if (threadIdx.x < (unsigned)s) {
            red0[threadIdx.x] += red0[threadIdx.x + s];
            red1[threadIdx.x] += red1[threadIdx.x + s];
        }
        __syncthreads();
    }
    if (threadIdx.x == 0) outp[0] = expf(red0[0]) + expf(red1[0]);
}

extern "C" void kernel_launch(void* const* d_in, const int* in_sizes, int n_in,
                              void* d_out, int out_size, void* d_ws, size_t ws_size,
                              hipStream_t stream) {
    const float* x      = (const float*)d_in[0];
    const float* gumbel = (const float*)d_in[1];
    const float* Wq     = (const float*)d_in[2];
    const float* bq     = (const float*)d_in[3];
    const float* cv     = (const float*)d_in[4];
    float* out = (float*)d_out;

    const int NT = in_sizes[0] / HID;       // 32768 tokens

    char* wsc = (char*)d_ws;
    float* meanAcc = (float*)wsc;                          // 640 f
    int*   cnt     = (int*)(wsc + 2560);                   // 2 ints
    int*   flags0  = (int*)(wsc + 4096);                   // 32768 ints
    int*   flags1  = (int*)(wsc + 135168);                 // 32768 ints
    unsigned short* Wb = (unsigned short*)(wsc + 266240);  // 640*512 bf16
    const size_t base = 921600;

    size_t avail = ws_size > base ? ws_size - base : 0;
    long maxTok = (long)(avail / 3584);
    int CH = (int)((maxTok / 128) * 128);
    if (CH > NT) CH = NT;
    if (CH < 128) CH = 128;
    unsigned short* Xb = (unsigned short*)(wsc + base);
    float* Lbuf = (float*)(wsc + base + (size_t)CH * 1024);

    zero_misc<<<1, 256, 0, stream>>>(meanAcc, cnt);
    convert_bf16<<<(GC * HID / 8 + 255) / 256, 256, 0, stream>>>(Wq, Wb, GC * HID / 8);

    for (int t0 = 0; t0 < NT; t0 += CH) {
        int cur = NT - t0 < CH ? NT - t0 : CH;
        int n8 = cur * HID / 8;
        convert_bf16<<<(n8 + 255) / 256, 256, 0, stream>>>(
            x + (size_t)t0 * HID, Xb, n8);
        dim3 ggrid(cur / 128, GC / 128);
        gemm_bf16<<<ggrid, 256, 0, stream>>>(Xb, Wb, bq, Lbuf);
        postproc<<<cur / 32, 512, 0, stream>>>(Lbuf, gumbel, cv, out, meanAcc, cnt,
                                               flags0, flags1, t0);
    }
    fixup<<<256, 320, 0, stream>>>(x, Wq, bq, gumbel, cv, out, flags0, flags1, cnt);
    perpk<<<1, 256, 0, stream>>>(meanAcc, out + (size_t)out_size - 1, NT);
}

// Round 5
// 141.433 us; speedup vs baseline: 3.1318x; 1.2375x over previous
//
#include <hip/hip_runtime.h>
#include <hip/hip_fp16.h>

#define HID 512
#define GC  640
#define CC  320
#define GG  2
#define DHALF 128
#define MARGIN 0.004f
#define FB 4

typedef __attribute__((ext_vector_type(8))) _Float16 half8;
typedef __attribute__((ext_vector_type(4))) float float4v;

__device__ __forceinline__ void gload16(const void* g, void* l) {
    __builtin_amdgcn_global_load_lds(
        (const __attribute__((address_space(1))) void*)(unsigned long long)g,
        (__attribute__((address_space(3))) void*)(unsigned)(unsigned long long)l,
        16, 0, 0);
}

__global__ __launch_bounds__(256) void zero_misc(float* meanAcc, int* cnt) {
    for (int i = threadIdx.x; i < GC; i += 256) meanAcc[i] = 0.f;
    if (threadIdx.x < 2) cnt[threadIdx.x] = 0;
}

__global__ __launch_bounds__(256) void convert_f16(
    const float* __restrict__ in, unsigned short* __restrict__ out, int n8)
{
    int i = blockIdx.x * 256 + threadIdx.x;
    if (i >= n8) return;
    const float4* p = (const float4*)in + (size_t)i * 2;
    float4 v0 = p[0], v1 = p[1];
    float f[8] = {v0.x, v0.y, v0.z, v0.w, v1.x, v1.y, v1.z, v1.w};
    unsigned r[4];
#pragma unroll
    for (int j = 0; j < 4; ++j) {
        __half2 hh = __float22half2_rn(make_float2(f[2*j], f[2*j+1]));
        r[j] = __builtin_bit_cast(unsigned, hh);
    }
    uint4 o = {r[0], r[1], r[2], r[3]};
    *(uint4*)(out + (size_t)i * 8) = o;
}

// C[m][n] = sum_k Xh[m][k] * Wh[n][k] (+ bq), fp16 MFMA
__global__ __launch_bounds__(256) void gemm_f16(
    const unsigned short* __restrict__ Xh,
    const unsigned short* __restrict__ Wh,
    const float* __restrict__ bq,
    float* __restrict__ L)
{
    __shared__ __align__(16) unsigned short As[128 * 32];
    __shared__ __align__(16) unsigned short Bs[128 * 32];
    const int tid  = threadIdx.x;
    const int lane = tid & 63;
    const int wid  = tid >> 6;
    const int wr   = wid >> 1, wc = wid & 1;
    const int brow = blockIdx.x * 128;
    const int bcol = blockIdx.y * 128;

    float4v acc[4][4] = {};

    const int chunk = (wid * 2) * 64 + lane;
    const int rowA0 = (chunk >> 2);
    const int k8A0  = (chunk & 3) * 8;
    const int chunk1 = (wid * 2 + 1) * 64 + lane;
    const int rowA1 = (chunk1 >> 2);
    const int k8A1  = (chunk1 & 3) * 8;

    for (int k0 = 0; k0 < HID; k0 += 32) {
        gload16(Xh + (size_t)(brow + rowA0) * HID + k0 + k8A0, &As[(wid * 2 + 0) * 512]);
        gload16(Xh + (size_t)(brow + rowA1) * HID + k0 + k8A1, &As[(wid * 2 + 1) * 512]);
        gload16(Wh + (size_t)(bcol + rowA0) * HID + k0 + k8A0, &Bs[(wid * 2 + 0) * 512]);
        gload16(Wh + (size_t)(bcol + rowA1) * HID + k0 + k8A1, &Bs[(wid * 2 + 1) * 512]);
        __syncthreads();
        half8 a[4], b[4];
#pragma unroll
        for (int t = 0; t < 4; ++t) {
            a[t] = *(const half8*)(const void*)&As[(wr * 64 + t * 16 + (lane & 15)) * 32 + (lane >> 4) * 8];
            b[t] = *(const half8*)(const void*)&Bs[(wc * 64 + t * 16 + (lane & 15)) * 32 + (lane >> 4) * 8];
        }
#pragma unroll
        for (int mt = 0; mt < 4; ++mt)
#pragma unroll
            for (int nt = 0; nt < 4; ++nt)
                acc[mt][nt] = __builtin_amdgcn_mfma_f32_16x16x32_f16(a[mt], b[nt], acc[mt][nt], 0, 0, 0);
        __syncthreads();
    }
#pragma unroll
    for (int mt = 0; mt < 4; ++mt) {
#pragma unroll
        for (int nt = 0; nt < 4; ++nt) {
            int col = bcol + wc * 64 + nt * 16 + (lane & 15);
            float bias = bq[col];
#pragma unroll
            for (int r = 0; r < 4; ++r) {
                int row = brow + wr * 64 + mt * 16 + (lane >> 4) * 4 + r;
                L[(size_t)row * GC + col] = acc[mt][nt][r] + bias;
            }
        }
    }
}

// 512 threads = 8 waves; waves 0-3 -> group 0, waves 4-7 -> group 1.
// Each token handled by a 16-lane group (20 contiguous codes per lane);
// 4 tokens in flight per wave, 4 iterations -> 16 tokens/wave, 64 tokens/block.
__global__ __launch_bounds__(512) void postproc(
    const float* __restrict__ L, const float* __restrict__ gum,
    const float* __restrict__ cv, float* __restrict__ out,
    float* __restrict__ meanAcc, int* __restrict__ cnt,
    int* __restrict__ flags0, int* __restrict__ flags1, int tok0)
{
    __shared__ float smean[GC];
    for (int i = threadIdx.x; i < GC; i += 512) smean[i] = 0.f;
    __syncthreads();

    const int lane = threadIdx.x & 63;
    const int wid  = threadIdx.x >> 6;      // 0..7
    const int g    = wid >> 2;              // group
    const int lq   = lane & 15;             // lane within 16-group
    const int tq   = lane >> 4;             // token slot 0..3
    const int c0   = lq * 20;               // first code owned by this lane
    int* flagsg = g ? flags1 : flags0;

    float macc[20];
#pragma unroll
    for (int j = 0; j < 20; ++j) macc[j] = 0.f;

    for (int it = 0; it < 4; ++it) {
        const int tloc  = blockIdx.x * 64 + (wid & 3) * 16 + it * 4 + tq;
        const int tglob = tok0 + tloc;
        const float* lrow = L   + (size_t)tloc * GC + g * CC + c0;
        const float* grow = gum + ((size_t)tglob * GG + g) * CC + c0;

        float le[20], ve[20];
#pragma unroll
        for (int jj = 0; jj < 5; ++jj) {
            float4 lv = *(const float4*)(lrow + jj * 4);
            float4 gv = *(const float4*)(grow + jj * 4);
            le[jj*4+0] = lv.x; le[jj*4+1] = lv.y; le[jj*4+2] = lv.z; le[jj*4+3] = lv.w;
            ve[jj*4+0] = lv.x + gv.x; ve[jj*4+1] = lv.y + gv.y;
            ve[jj*4+2] = lv.z + gv.z; ve[jj*4+3] = lv.w + gv.w;
        }
        // exp (no max-sub: logits ~N(0,1), |max| < ~6) and per-lane sum
        float s = 0.f;
#pragma unroll
        for (int j = 0; j < 20; ++j) { le[j] = __expf(le[j]); s += le[j]; }
        // per-lane top-2
        float b = ve[0]; int bi = c0; float s2 = -3.0e38f;
#pragma unroll
        for (int j = 1; j < 20; ++j) {
            float v = ve[j];
            if (v > b) { s2 = b; b = v; bi = c0 + j; }
            else if (v > s2) s2 = v;
        }
        // fused 4-step reduce within the 16-lane group: sum + (max, idx, second)
#pragma unroll
        for (int m = 1; m < 16; m <<= 1) {
            float os  = __shfl_xor(s,  m, 64);
            float ob  = __shfl_xor(b,  m, 64);
            int   obi = __shfl_xor(bi, m, 64);
            float os2 = __shfl_xor(s2, m, 64);
            s += os;
            if (ob > b || (ob == b && obi < bi)) { s2 = fmaxf(os2, b); b = ob; bi = obi; }
            else                                 { s2 = fmaxf(s2, ob); }
        }
        float inv = 1.f / s;
#pragma unroll
        for (int j = 0; j < 20; ++j) macc[j] += le[j] * inv;

        if (lq == 0 && (b - s2) < MARGIN) {
            int p = atomicAdd(&cnt[g], 1);
            flagsg[p] = tglob;
        }
        // gather selected codevector: 16 lanes x 8 floats = 128, coalesced
        const float* cvp = cv + ((size_t)(g * CC + bi)) * DHALF + lq * 8;
        float4 c0v = *(const float4*)cvp;
        float4 c1v = *(const float4*)(cvp + 4);
        float* op = out + (size_t)tglob * 256 + g * DHALF + lq * 8;
        *(float4*)op       = c0v;
        *(float4*)(op + 4) = c1v;
    }
    // fold macc across the 4 token-slots of this wave (lanes share lq columns)
#pragma unroll
    for (int j = 0; j < 20; ++j) {
        macc[j] += __shfl_xor(macc[j], 16, 64);
        macc[j] += __shfl_xor(macc[j], 32, 64);
    }
    if (lane < 16) {
#pragma unroll
        for (int j = 0; j < 20; ++j)
            atomicAdd(&smean[g * CC + c0 + j], macc[j]);
    }
    __syncthreads();
    for (int i = threadIdx.x; i < GC; i += 512)
        atomicAdd(&meanAcc[i], smean[i]);
}

// Exact fp32 recompute for flagged rows: FB rows share one W pass.
__global__ __launch_bounds__(320) void fixup(
    const float* __restrict__ X, const float* __restrict__ W,
    const float* __restrict__ bq, const float* __restrict__ gum,
    const float* __restrict__ cv, float* __restrict__ out,
    const int* __restrict__ flags0, const int* __restrict__ flags1,
    const int* __restrict__ cnt)
{
    __shared__ float xs[FB][HID];
    __shared__ float vals[FB][CC];
    __shared__ int stok[FB];
    const int tid = threadIdx.x;
    const int n0 = cnt[0], n1 = cnt[1];
    const int nb0 = (n0 + FB - 1) / FB;
    const int nb1 = (n1 + FB - 1) / FB;

    for (int bb = blockIdx.x; bb < nb0 + nb1; bb += gridDim.x) {
        const int g    = (bb < nb0) ? 0 : 1;
        const int lb   = (bb < nb0) ? bb : bb - nb0;
        const int n    = g ? n1 : n0;
        const int* fl  = g ? flags1 : flags0;
        const int r0   = lb * FB;
        const int nr   = (n - r0 < FB) ? (n - r0) : FB;

        if (tid < FB) {
            int idx = r0 + tid;
            if (idx >= n) idx = n - 1;
            stok[tid] = fl[idx];
        }
        __syncthreads();
        for (int i = tid; i < FB * (HID / 4); i += 320) {
            int r = i >> 7, k4 = i & 127;
            *(float4*)&xs[r][k4 * 4] = *(const float4*)(X + (size_t)stok[r] * HID + k4 * 4);
        }
        __syncthreads();

        {
            const int c = tid;
            if (c < CC) {
                const float* wr = W + (size_t)(g * CC + c) * HID;
                float acc[FB];
#pragma unroll
                for (int r = 0; r < FB; ++r) acc[r] = 0.f;
                for (int k4 = 0; k4 < HID / 4; ++k4) {
                    float4 w4 = *(const float4*)(wr + k4 * 4);
#pragma unroll
                    for (int r = 0; r < FB; ++r) {
                        float4 xv = *(const float4*)&xs[r][k4 * 4];
                        acc[r] = fmaf(xv.x, w4.x, acc[r]);
                        acc[r] = fmaf(xv.y, w4.y, acc[r]);
                        acc[r] = fmaf(xv.z, w4.z, acc[r]);
                        acc[r] = fmaf(xv.w, w4.w, acc[r]);
                    }
                }
                float bias = bq[g * CC + c];
#pragma unroll
                for (int r = 0; r < FB; ++r)
                    vals[r][c] = acc[r] + bias + gum[((size_t)stok[r] * GG + g) * CC + c];
            }
        }
        __syncthreads();

        const int lane = tid & 63;
        const int wv   = tid >> 6;
        if (wv < FB) {
            const int r = wv;
            if (r < nr) {
                float b = -3.0e38f; int bi = 0;
#pragma unroll
                for (int j = 0; j < 5; ++j) {
                    int c = lane + j * 64;
                    float v = vals[r][c];
                    if (v > b || (v == b && c < bi)) { b = v; bi = c; }
                }
#pragma unroll
                for (int m = 32; m; m >>= 1) {
                    float ob = __shfl_xor(b, m, 64);
                    int  obi = __shfl_xor(bi, m, 64);
                    if (ob > b || (ob == b && obi < bi)) { b = ob; bi = obi; }
                }
                int tok = stok[r];
                float2 cvv = *(const float2*)(cv + ((size_t)(g * CC + bi)) * DHALF + lane * 2);
                *(float2*)(out + (size_t)tok * 256 + g * DHALF + lane * 2) = cvv;
            }
        }
        __syncthreads();
    }
}

__global__ __launch_bounds__(256) void perpk(
    const float* __restrict__ meanAcc, float* __restrict__ outp, int ntot)
{
    __shared__ float red0[256];
    __shared__ float red1[256];
    const float invn = 1.f / (float)ntot;
    float h0 = 0.f, h1 = 0.f;
    for (int c = threadIdx.x; c < CC; c += 256) {
        float p0 = meanAcc[c]      * invn;
        float p1 = meanAcc[CC + c] * invn;
        h0 -= p0 * logf(p0 + 1e-7f);
        h1 -= p1 * logf(p1 + 1e-7f);
    }
    red0[threadIdx.x] = h0; red1[threadIdx.x] = h1;
    __syncthreads();
    for (int s = 128; s; s >>= 1) {
        if (threadIdx.x < (unsigned)s) {
            red0[threadIdx.x] += red0[threadIdx.x + s];
            red1[threadIdx.x] += red1[threadIdx.x + s];
        }
        __syncthreads();
    }
    if (threadIdx.x == 0) outp[0] = expf(red0[0]) + expf(red1[0]);
}

extern "C" void kernel_launch(void* const* d_in, const int* in_sizes, int n_in,
                              void* d_out, int out_size, void* d_ws, size_t ws_size,
                              hipStream_t stream) {
    const float* x      = (const float*)d_in[0];
    const float* gumbel = (const float*)d_in[1];
    const float* Wq     = (const float*)d_in[2];
    const float* bq     = (const float*)d_in[3];
    const float* cv     = (const float*)d_in[4];
    float* out = (float*)d_out;

    const int NT = in_sizes[0] / HID;       // 32768 tokens

    char* wsc = (char*)d_ws;
    float* meanAcc = (float*)wsc;                          // 640 f
    int*   cnt     = (int*)(wsc + 2560);                   // 2 ints
    int*   flags0  = (int*)(wsc + 4096);                   // 32768 ints
    int*   flags1  = (int*)(wsc + 135168);                 // 32768 ints
    unsigned short* Wh = (unsigned short*)(wsc + 266240);  // 640*512 f16
    const size_t base = 921600;

    size_t avail = ws_size > base ? ws_size - base : 0;
    long maxTok = (long)(avail / 3584);
    int CH = (int)((maxTok / 128) * 128);
    if (CH > NT) CH = NT;
    if (CH < 128) CH = 128;
    unsigned short* Xh = (unsigned short*)(wsc + base);
    float* Lbuf = (float*)(wsc + base + (size_t)CH * 1024);

    zero_misc<<<1, 256, 0, stream>>>(meanAcc, cnt);
    convert_f16<<<(GC * HID / 8 + 255) / 256, 256, 0, stream>>>(Wq, Wh, GC * HID / 8);

    for (int t0 = 0; t0 < NT; t0 += CH) {
        int cur = NT - t0 < CH ? NT - t0 : CH;
        int n8 = cur * HID / 8;
        convert_f16<<<(n8 + 255) / 256, 256, 0, stream>>>(
            x + (size_t)t0 * HID, Xh, n8);
        dim3 ggrid(cur / 128, GC / 128);
        gemm_f16<<<ggrid, 256, 0, stream>>>(Xh, Wh, bq, Lbuf);
        postproc<<<cur / 64, 512, 0, stream>>>(Lbuf, gumbel, cv, out, meanAcc, cnt,
                                               flags0, flags1, t0);
    }
    fixup<<<256, 320, 0, stream>>>(x, Wq, bq, gumbel, cv, out, flags0, flags1, cnt);
    perpk<<<1, 256, 0, stream>>>(meanAcc, out + (size_t)out_size - 1, NT);
}

// Round 6
// 116.773 us; speedup vs baseline: 3.7931x; 1.2112x over previous
//
#include <hip/hip_runtime.h>
#include <hip/hip_fp16.h>

#define HID 512
#define GC  640
#define CC  320
#define GG  2
#define DHALF 128
#define MARGIN 0.004f
#define FB 4

typedef __attribute__((ext_vector_type(8))) _Float16 half8;
typedef __attribute__((ext_vector_type(4))) float float4v;

__device__ __forceinline__ void gload16(const void* g, void* l) {
    __builtin_amdgcn_global_load_lds(
        (const __attribute__((address_space(1))) void*)(unsigned long long)g,
        (__attribute__((address_space(3))) void*)(unsigned)(unsigned long long)l,
        16, 0, 0);
}

__global__ __launch_bounds__(256) void zero_misc(float* meanAcc, int* cnt) {
    for (int i = threadIdx.x; i < GC; i += 256) meanAcc[i] = 0.f;
    if (threadIdx.x < 2) cnt[threadIdx.x] = 0;
}

__global__ __launch_bounds__(256) void convert_f16(
    const float* __restrict__ in, unsigned short* __restrict__ out, int n8)
{
    int i = blockIdx.x * 256 + threadIdx.x;
    if (i >= n8) return;
    const float4* p = (const float4*)in + (size_t)i * 2;
    float4 v0 = p[0], v1 = p[1];
    float f[8] = {v0.x, v0.y, v0.z, v0.w, v1.x, v1.y, v1.z, v1.w};
    unsigned r[4];
#pragma unroll
    for (int j = 0; j < 4; ++j) {
        __half2 hh = __float22half2_rn(make_float2(f[2*j], f[2*j+1]));
        r[j] = __builtin_bit_cast(unsigned, hh);
    }
    uint4 o = {r[0], r[1], r[2], r[3]};
    *(uint4*)(out + (size_t)i * 8) = o;
}

// Fused: convert-X + GEMM (fp16 MFMA) + softmax-mean + argmax + gather.
// Block: 128 tokens x 320 codes (group = swz&1). 8 waves, each wave owns
// 16 rows x 320 cols = 20 n-frags of 16x16x32. Softmax fully in-register.
__global__ __launch_bounds__(512, 4) void fused(
    const float* __restrict__ X, const unsigned short* __restrict__ Wh,
    const float* __restrict__ bq, const float* __restrict__ gum,
    const float* __restrict__ cv, float* __restrict__ out,
    float* __restrict__ meanAcc, int* __restrict__ cnt,
    int* __restrict__ flags0, int* __restrict__ flags1)
{
    __shared__ __align__(16) unsigned short As[128 * 32];   // 8 KB
    __shared__ __align__(16) unsigned short Bs[384 * 32];   // 24 KB (64 pad rows)
    __shared__ float bqs[CC];
    __shared__ float smean[CC];

    const int tid  = threadIdx.x;
    const int lane = tid & 63;
    const int wid  = tid >> 6;          // 0..7
    const int lq   = lane & 15;
    const int q    = lane >> 4;

    // XCD-aware swizzle: (tok,g=0)/(tok,g=1) pairs land on the same XCD
    int bid = blockIdx.x;
    int nwg = gridDim.x;
    int swz = ((nwg & 7) == 0) ? (bid & 7) * (nwg >> 3) + (bid >> 3) : bid;
    const int g    = swz & 1;
    const int tok0 = (swz >> 1) * 128;
    int* flagsg = g ? flags1 : flags0;

    for (int i = tid; i < CC; i += 512) { bqs[i] = bq[g * CC + i]; smean[i] = 0.f; }

    float4v acc[20];
#pragma unroll
    for (int j = 0; j < 20; ++j) acc[j] = (float4v){0.f, 0.f, 0.f, 0.f};

    // A staging: thread t handles (row = t>>2, slot = t&3), 8 floats -> 8 halfs
    const int arow = tid >> 2, aslot = tid & 3;
    const float* xsrc = X + (size_t)(tok0 + arow) * HID + aslot * 8;

    for (int k0 = 0; k0 < HID; k0 += 32) {
        float4 xa = *(const float4*)(xsrc + k0);
        float4 xb = *(const float4*)(xsrc + k0 + 4);
        half8 h;
        h[0] = (_Float16)xa.x; h[1] = (_Float16)xa.y;
        h[2] = (_Float16)xa.z; h[3] = (_Float16)xa.w;
        h[4] = (_Float16)xb.x; h[5] = (_Float16)xb.y;
        h[6] = (_Float16)xb.z; h[7] = (_Float16)xb.w;
        *(half8*)&As[arow * 32 + aslot * 8] = h;
        // B staging: 24 gload issues of 1KB; 3 per wave; rows >=320 clamped (never read)
#pragma unroll
        for (int ii = 0; ii < 3; ++ii) {
            const int iss = wid * 3 + ii;
            int e  = iss * 64 + lane;
            int br = e >> 2; if (br > 319) br = 319;
            int bs = e & 3;
            gload16(Wh + ((size_t)(g * CC + br)) * HID + k0 + bs * 8,
                    &Bs[iss * 512]);
        }
        __syncthreads();
        half8 a = *(const half8*)&As[(wid * 16 + lq) * 32 + q * 8];
#pragma unroll
        for (int j = 0; j < 20; ++j) {
            half8 b = *(const half8*)&Bs[(j * 16 + lq) * 32 + q * 8];
            acc[j] = __builtin_amdgcn_mfma_f32_16x16x32_f16(a, b, acc[j], 0, 0, 0);
        }
        __syncthreads();
    }

    // Epilogue: per reg r, the 4 q-groups each own one row (row = wid*16+q*4+r),
    // lane lq holds cols c = j*16+lq (ascending j => ascending c, tie -> lowest).
    float macc[20];
#pragma unroll
    for (int j = 0; j < 20; ++j) macc[j] = 0.f;

#pragma unroll
    for (int r = 0; r < 4; ++r) {
        const int rowL  = wid * 16 + q * 4 + r;
        const int tglob = tok0 + rowL;
        const float* grow = gum + ((size_t)tglob * GG + g) * CC;
        float le[20];
        float s = 0.f;
        float b = -3.0e38f; int bi = 0; float s2 = -3.0e38f;
#pragma unroll
        for (int j = 0; j < 20; ++j) {
            const int c = j * 16 + lq;
            float lg = acc[j][r] + bqs[c];
            float v  = lg + grow[c];
            if (v > b)       { s2 = b; b = v; bi = c; }
            else if (v > s2) { s2 = v; }
            le[j] = __expf(lg); s += le[j];
        }
        // fused 4-step reduce within the 16-lane group: sum + (max, idx, second)
#pragma unroll
        for (int m = 1; m < 16; m <<= 1) {
            float os  = __shfl_xor(s,  m, 64);
            float ob  = __shfl_xor(b,  m, 64);
            int   obi = __shfl_xor(bi, m, 64);
            float os2 = __shfl_xor(s2, m, 64);
            s += os;
            if (ob > b || (ob == b && obi < bi)) { s2 = fmaxf(os2, b); b = ob; bi = obi; }
            else                                 { s2 = fmaxf(s2, ob); }
        }
        float inv = 1.f / s;
#pragma unroll
        for (int j = 0; j < 20; ++j) macc[j] += le[j] * inv;

        if (lq == 0 && (b - s2) < MARGIN) {
            int p = atomicAdd(&cnt[g], 1);
            flagsg[p] = tglob;
        }
        // gather selected codevector: 16 lanes x 8 floats, coalesced
        const float* cvp = cv + ((size_t)(g * CC + bi)) * DHALF + lq * 8;
        float4 c0v = *(const float4*)cvp;
        float4 c1v = *(const float4*)(cvp + 4);
        float* op = out + (size_t)tglob * 256 + g * DHALF + lq * 8;
        *(float4*)op       = c0v;
        *(float4*)(op + 4) = c1v;
    }
    // fold across q-groups (same cols), then 16 lanes -> LDS, then global
#pragma unroll
    for (int j = 0; j < 20; ++j) {
        macc[j] += __shfl_xor(macc[j], 16, 64);
        macc[j] += __shfl_xor(macc[j], 32, 64);
    }
    if (lane < 16) {
#pragma unroll
        for (int j = 0; j < 20; ++j)
            atomicAdd(&smean[j * 16 + lq], macc[j]);
    }
    __syncthreads();
    for (int i = tid; i < CC; i += 512)
        atomicAdd(&meanAcc[g * CC + i], smean[i]);
}

// Exact fp32 recompute for flagged rows: FB rows share one W pass.
__global__ __launch_bounds__(320) void fixup(
    const float* __restrict__ X, const float* __restrict__ W,
    const float* __restrict__ bq, const float* __restrict__ gum,
    const float* __restrict__ cv, float* __restrict__ out,
    const int* __restrict__ flags0, const int* __restrict__ flags1,
    const int* __restrict__ cnt)
{
    __shared__ float xs[FB][HID];
    __shared__ float vals[FB][CC];
    __shared__ int stok[FB];
    const int tid = threadIdx.x;
    const int n0 = cnt[0], n1 = cnt[1];
    const int nb0 = (n0 + FB - 1) / FB;
    const int nb1 = (n1 + FB - 1) / FB;

    for (int bb = blockIdx.x; bb < nb0 + nb1; bb += gridDim.x) {
        const int g    = (bb < nb0) ? 0 : 1;
        const int lb   = (bb < nb0) ? bb : bb - nb0;
        const int n    = g ? n1 : n0;
        const int* fl  = g ? flags1 : flags0;
        const int r0   = lb * FB;
        const int nr   = (n - r0 < FB) ? (n - r0) : FB;

        if (tid < FB) {
            int idx = r0 + tid;
            if (idx >= n) idx = n - 1;
            stok[tid] = fl[idx];
        }
        __syncthreads();
        for (int i = tid; i < FB * (HID / 4); i += 320) {
            int r = i >> 7, k4 = i & 127;
            *(float4*)&xs[r][k4 * 4] = *(const float4*)(X + (size_t)stok[r] * HID + k4 * 4);
        }
        __syncthreads();

        {
            const int c = tid;
            if (c < CC) {
                const float* wr = W + (size_t)(g * CC + c) * HID;
                float acc[FB];
#pragma unroll
                for (int r = 0; r < FB; ++r) acc[r] = 0.f;
                for (int k4 = 0; k4 < HID / 4; ++k4) {
                    float4 w4 = *(const float4*)(wr + k4 * 4);
#pragma unroll
                    for (int r = 0; r < FB; ++r) {
                        float4 xv = *(const float4*)&xs[r][k4 * 4];
                        acc[r] = fmaf(xv.x, w4.x, acc[r]);
                        acc[r] = fmaf(xv.y, w4.y, acc[r]);
                        acc[r] = fmaf(xv.z, w4.z, acc[r]);
                        acc[r] = fmaf(xv.w, w4.w, acc[r]);
                    }
                }
                float bias = bq[g * CC + c];
#pragma unroll
                for (int r = 0; r < FB; ++r)
                    vals[r][c] = acc[r] + bias + gum[((size_t)stok[r] * GG + g) * CC + c];
            }
        }
        __syncthreads();

        const int lane = tid & 63;
        const int wv   = tid >> 6;
        if (wv < FB) {
            const int r = wv;
            if (r < nr) {
                float b = -3.0e38f; int bi = 0;
#pragma unroll
                for (int j = 0; j < 5; ++j) {
                    int c = lane + j * 64;
                    float v = vals[r][c];
                    if (v > b || (v == b && c < bi)) { b = v; bi = c; }
                }
#pragma unroll
                for (int m = 32; m; m >>= 1) {
                    float ob = __shfl_xor(b, m, 64);
                    int  obi = __shfl_xor(bi, m, 64);
                    if (ob > b || (ob == b && obi < bi)) { b = ob; bi = obi; }
                }
                int tok = stok[r];
                float2 cvv = *(const float2*)(cv + ((size_t)(g * CC + bi)) * DHALF + lane * 2);
                *(float2*)(out + (size_t)tok * 256 + g * DHALF + lane * 2) = cvv;
            }
        }
        __syncthreads();
    }
}

__global__ __launch_bounds__(256) void perpk(
    const float* __restrict__ meanAcc, float* __restrict__ outp, int ntot)
{
    __shared__ float red0[256];
    __shared__ float red1[256];
    const float invn = 1.f / (float)ntot;
    float h0 = 0.f, h1 = 0.f;
    for (int c = threadIdx.x; c < CC; c += 256) {
        float p0 = meanAcc[c]      * invn;
        float p1 = meanAcc[CC + c] * invn;
        h0 -= p0 * logf(p0 + 1e-7f);
        h1 -= p1 * logf(p1 + 1e-7f);
    }
    red0[threadIdx.x] = h0; red1[threadIdx.x] = h1;
    __syncthreads();
    for (int s = 128; s; s >>= 1) {
        if (threadIdx.x < (unsigned)s) {
            red0[threadIdx.x] += red0[threadIdx.x + s];
            red1[threadIdx.x] += red1[threadIdx.x + s];
        }
        __syncthreads();
    }
    if (threadIdx.x == 0) outp[0] = expf(red0[0]) + expf(red1[0]);
}

extern "C" void kernel_launch(void* const* d_in, const int* in_sizes, int n_in,
                              void* d_out, int out_size, void* d_ws, size_t ws_size,
                              hipStream_t stream) {
    const float* x      = (const float*)d_in[0];
    const float* gumbel = (const float*)d_in[1];
    const float* Wq     = (const float*)d_in[2];
    const float* bq     = (const float*)d_in[3];
    const float* cv     = (const float*)d_in[4];
    float* out = (float*)d_out;

    const int NT = in_sizes[0] / HID;       // 32768 tokens

    char* wsc = (char*)d_ws;
    float* meanAcc = (float*)wsc;                          // 640 f
    int*   cnt     = (int*)(wsc + 2560);                   // 2 ints
    int*   flags0  = (int*)(wsc + 4096);                   // 32768 ints
    int*   flags1  = (int*)(wsc + 135168);                 // 32768 ints
    unsigned short* Wh = (unsigned short*)(wsc + 266240);  // 640*512 f16

    zero_misc<<<1, 256, 0, stream>>>(meanAcc, cnt);
    convert_f16<<<(GC * HID / 8 + 255) / 256, 256, 0, stream>>>(Wq, Wh, GC * HID / 8);

    const int nwg = (NT / 128) * 2;         // 512 blocks = 2 per CU
    fused<<<nwg, 512, 0, stream>>>(x, Wh, bq, gumbel, cv, out,
                                   meanAcc, cnt, flags0, flags1);

    fixup<<<256, 320, 0, stream>>>(x, Wq, bq, gumbel, cv, out, flags0, flags1, cnt);
    perpk<<<1, 256, 0, stream>>>(meanAcc, out + (size_t)out_size - 1, NT);
}